// Round 8
// baseline (441.438 us; speedup 1.0000x reference)
//
#include <hip/hip_runtime.h>

#define VOCAB 21
#define EMB 128
#define H1 64
#define H2 100
#define T1 500
#define TP 100
#define NB 1024
#define TBL_LD 260   // words; 260 mod 32 = 4 -> rows land on different banks
#define LOG2E 1.44269504f

typedef __attribute__((ext_vector_type(8))) short bf16x8;
typedef __attribute__((ext_vector_type(4))) float f32x4;

__device__ __forceinline__ unsigned short f2bf(float x){
    union { float f; unsigned u; } v; v.f = x;
    return (unsigned short)((v.u + 0x8000u) >> 16);
}
// LDS-only barrier: do NOT drain vmcnt (global stores/loads stay in flight)
__device__ __forceinline__ void bar_lds(){
    asm volatile("s_waitcnt lgkmcnt(0)\n\ts_barrier" ::: "memory");
}
__device__ __forceinline__ float ex2(float x){ return __builtin_amdgcn_exp2f(x); }
__device__ __forceinline__ float rcp(float x){ return __builtin_amdgcn_rcpf(x); }

// ---------------------------------------------------------------------------
// Kernel 0: permuted xproj table, pre-scaled by log2(e), padded stride.
// table[v][4*cell+gate] = LOG2E*(dot(W_ih1[gate*64+cell,:], emb[v,:]) + b_ih1 + b_hh1)
// ---------------------------------------------------------------------------
__global__ void k_table(const float* __restrict__ Wih, const float* __restrict__ emb,
                        const float* __restrict__ bih, const float* __restrict__ bhh,
                        float* __restrict__ table){
    const int p = threadIdx.x;
    const int v = blockIdx.x;
    const int orig = (p & 3) * H1 + (p >> 2);
    float s = bih[orig] + bhh[orig];
    if (v != 0){
        const float* w = Wih + orig * EMB;
        const float* e = emb + v * EMB;
        #pragma unroll 16
        for (int d = 0; d < EMB; ++d) s += w[d]*e[d];
    }
    table[v*TBL_LD + p] = s * LOG2E;
}

// ---------------------------------------------------------------------------
// Kernel 1: layer-1 LSTM. 4 rows/block, 256 blocks, 4 waves.
// Wave w owns gate tiles 4w..4w+3 == cells 16w..16w+15. PRODUCER-DIRECT:
// lanes n<4 consume their own MFMA acc quads (4 cells each) — no gate LDS
// round-trip. xproj table quad is the MFMA C-init. One lgkm-barrier/step.
// ---------------------------------------------------------------------------
__global__ __launch_bounds__(256, 1) void k_lstm1(
    const int* __restrict__ xidx, const float* __restrict__ Whh,
    const float* __restrict__ tbl_g, float* __restrict__ x2){
  __shared__ __align__(16) float table[VOCAB*TBL_LD];    // 21840 B
  __shared__ __align__(16) unsigned short hbuf[2][16*64];// 4096 B (XOR-swizzled)
  __shared__ int idxs[4*T1];                             // 8000 B

  const int tid = threadIdx.x;
  const int w = tid >> 6, l = tid & 63;
  const int b0 = blockIdx.x * 4;
  const int n = l & 15, kg = l >> 4;

  for (int i = tid; i < VOCAB*TBL_LD; i += 256) table[i] = tbl_g[i];
  for (int i = tid; i < 4*T1; i += 256){
      int r = i / T1, t = i - r*T1;
      idxs[i] = xidx[(b0 + r)*T1 + t];
  }
  { unsigned short* hz = (unsigned short*)hbuf;
    for (int i = tid; i < 2048; i += 256) hz[i] = 0; }

  // A fragments (permuted Whh * LOG2E): tiles gt=4w+u
  bf16x8 af[4][2];
  #pragma unroll
  for (int u = 0; u < 4; ++u){
      const int p = 16*(4*w + u) + n;
      const int orig = (p & 3)*H1 + (p >> 2);
      #pragma unroll
      for (int c = 0; c < 2; ++c){
          const float* src = Whh + orig*H1 + c*32 + kg*8;
          bf16x8 f;
          #pragma unroll
          for (int j = 0; j < 8; ++j) f[j] = (short)f2bf(src[j] * LOG2E);
          af[u][c] = f;
      }
  }

  char* hb = (char*)hbuf;
  const int swz = (n & 7) << 4;
  const int rb0 = (n*128 + 16*kg) ^ swz;
  const int rb1 = (n*128 + 64 + 16*kg) ^ swz;
  const bool prod = (n < 4);
  const int rowc = n & 3;                      // clamped row for junk lanes
  int cu[4], whb[4];
  #pragma unroll
  for (int u = 0; u < 4; ++u){
      cu[u] = 16*w + 4*u + kg;
      whb[u] = (n*128 + 2*cu[u]) ^ swz;        // valid when prod
  }
  const float twoL = 2.0f * LOG2E;

  float cc[4] = {0.f,0.f,0.f,0.f};
  float pm[4] = {-1e30f,-1e30f,-1e30f,-1e30f};
  __syncthreads();

  int vv = idxs[rowc*T1];
  f32x4 tq[4];
  #pragma unroll
  for (int u = 0; u < 4; ++u) tq[u] = *(const f32x4*)&table[vv*TBL_LD + 4*cu[u]];
  int vnext = idxs[rowc*T1 + 1];
  const f32x4 z4 = {0.f, 0.f, 0.f, 0.f};

  int rp = 0, tm = 0, tp = 0;
  for (int t = 0; t < T1; ++t){
      bf16x8 bf0 = *(const bf16x8*)(hb + rp + rb0);
      bf16x8 bf1 = *(const bf16x8*)(hb + rp + rb1);
      // off-chain: prefetch next step's table quads + idx
      f32x4 tqn[4];
      #pragma unroll
      for (int u = 0; u < 4; ++u)
          tqn[u] = *(const f32x4*)&table[vnext*TBL_LD + 4*cu[u]];
      int vn2 = idxs[rowc*T1 + ((t + 2 < T1) ? (t + 2) : 0)];
      // MFMA, split accumulators, xproj as C-init
      f32x4 z[4];
      #pragma unroll
      for (int u = 0; u < 4; ++u){
          f32x4 a = __builtin_amdgcn_mfma_f32_16x16x32_bf16(af[u][0], bf0, tq[u], 0,0,0);
          f32x4 b = __builtin_amdgcn_mfma_f32_16x16x32_bf16(af[u][1], bf1, z4, 0,0,0);
          z[u] = a + b;
      }
      const int wp = rp ^ 2048;
      ++tm;
      if (prod){
          #pragma unroll
          for (int u = 0; u < 4; ++u){
              float si = rcp(1.f + ex2(-z[u][0]));
              float sf = rcp(1.f + ex2(-z[u][1]));
              float so = rcp(1.f + ex2(-z[u][3]));
              float tg = 1.f - 2.f*rcp(1.f + ex2(z[u][2] + z[u][2]));
              cc[u] = sf*cc[u] + si*tg;
              float th = 1.f - 2.f*rcp(1.f + ex2(twoL*cc[u]));
              float h = so*th;
              *(unsigned short*)(hb + wp + whb[u]) = f2bf(h);
              pm[u] = fmaxf(pm[u], h);
          }
          if (tm == 5){
              float* dst = x2 + (b0 + n)*(TP*H1) + tp*H1;
              #pragma unroll
              for (int u = 0; u < 4; ++u) dst[cu[u]] = pm[u];  // async stores
              #pragma unroll
              for (int u = 0; u < 4; ++u) pm[u] = -1e30f;
          }
      }
      if (tm == 5){ tm = 0; ++tp; }
      #pragma unroll
      for (int u = 0; u < 4; ++u) tq[u] = tqn[u];
      vnext = vn2;
      rp = wp;
      bar_lds();
  }
}

// ---------------------------------------------------------------------------
// Kernel 2: layer-2 LSTM. 4 rows/block, 256 blocks, 8 waves; 26 tiles split
// 4,4,3,3,3,3,3,3. Producer-direct activation (no gate LDS), split-acc MFMA,
// DEPTH-2 x prefetch (x2 is L3-resident, ~600cy — must span a full step).
// ---------------------------------------------------------------------------
__global__ __launch_bounds__(512, 1) void k_lstm2(
    const float* __restrict__ x2, const float* __restrict__ Wih,
    const float* __restrict__ Whh, const float* __restrict__ bih,
    const float* __restrict__ bhh, const float* __restrict__ fcw,
    const float* __restrict__ fcb, float* __restrict__ out){
  __shared__ __align__(16) unsigned short blds[2][16*192];   // 12288 B
  __shared__ float fcred[8][4];

  const int tid = threadIdx.x;
  const int w = tid >> 6, l = tid & 63;
  const int b0 = blockIdx.x * 4;
  const int n = l & 15, kg = l >> 4;
  const int tlo = (w < 2) ? 4*w : 8 + 3*(w - 2);
  const int nt  = (w < 2) ? 4 : 3;

  { unsigned* bz0 = (unsigned*)blds;
    for (int i = tid; i < 3072; i += 512) bz0[i] = 0; }

  // A fragments: [W_ih2 | W_hh2] permuted * LOG2E, zero-padded
  bf16x8 af[4][6];
  #pragma unroll
  for (int u = 0; u < 4; ++u){
      if (u < nt){
          const int p = 16*(tlo + u) + n;
          const int cell_ = p >> 2, gate = p & 3;
          #pragma unroll
          for (int c = 0; c < 6; ++c){
              bf16x8 f;
              #pragma unroll
              for (int jj = 0; jj < 8; ++jj){
                  int k = c*32 + kg*8 + jj;
                  float vv = 0.f;
                  if (cell_ < H2){
                      if (k < 64)           vv = Wih[(gate*H2 + cell_)*H1 + k];
                      else if (k < 64 + H2) vv = Whh[(gate*H2 + cell_)*H2 + (k - 64)];
                  }
                  f[jj] = (short)f2bf(vv * LOG2E);
              }
              af[u][c] = f;
          }
      }
  }

  // bias C-init quads (producer layout: cell 4(tlo+u)+kg, gates in regs)
  f32x4 bz[4];
  int cu[4], whb[4];
  float fw[4];
  #pragma unroll
  for (int u = 0; u < 4; ++u){
      cu[u] = 4*(tlo + u) + kg;
      f32x4 b = {0.f,0.f,0.f,0.f};
      float fv = 0.f;
      if (u < nt && cu[u] < H2){
          #pragma unroll
          for (int g = 0; g < 4; ++g) b[g] = (bih[g*H2 + cu[u]] + bhh[g*H2 + cu[u]]) * LOG2E;
          fv = fcw[cu[u]];
      }
      bz[u] = b; fw[u] = fv;
      whb[u] = (n*384 + 2*(64 + cu[u])) ^ ((n & 7) << 4);
  }
  const bool prod = (n < 4);
  const float twoL = 2.0f * LOG2E;

  char* bb = (char*)blds;
  const int swz = (n & 7) << 4;
  int rb[6];
  #pragma unroll
  for (int c = 0; c < 6; ++c) rb[c] = (n*384 + 64*c + 16*kg) ^ swz;

  // x-staging: tid>=384 (waves 6,7): row xr, cells 2*xc,2*xc+1; depth-2 pipe
  const int xr = (tid >> 5) & 3, xc = tid & 31;
  const int xwb = (xr*384 + 4*xc) ^ (xr << 4);
  float2 xa = {0.f, 0.f};
  if (tid >= 384){
      float2 v = *(const float2*)&x2[(b0 + xr)*(TP*H1) + 2*xc];     // x(0)
      unsigned pk = (unsigned)f2bf(v.x) | ((unsigned)f2bf(v.y) << 16);
      *(unsigned*)(bb + xwb) = pk;
      xa = *(const float2*)&x2[(b0 + xr)*(TP*H1) + 1*H1 + 2*xc];    // x(1) in flight
  }
  float cc[4] = {0.f,0.f,0.f,0.f};
  float hv[4] = {0.f,0.f,0.f,0.f};
  __syncthreads();

  int rp = 0;
  for (int t = 0; t < TP; ++t){
      float2 xb_ = {0.f, 0.f};
      if (tid >= 384 && t + 2 < TP)              // issue 2 steps early
          xb_ = *(const float2*)&x2[(b0 + xr)*(TP*H1) + (t+2)*H1 + 2*xc];
      bf16x8 bf[6];
      #pragma unroll
      for (int c = 0; c < 6; ++c) bf[c] = *(const bf16x8*)(bb + rp + rb[c]);
      f32x4 z[4];
      #pragma unroll
      for (int u = 0; u < 4; ++u){
          if (u < nt){
              f32x4 za = __builtin_amdgcn_mfma_f32_16x16x32_bf16(af[u][0], bf[0], bz[u], 0,0,0);
              f32x4 zb = __builtin_amdgcn_mfma_f32_16x16x32_bf16(af[u][1], bf[1], (f32x4){0.f,0.f,0.f,0.f}, 0,0,0);
              za = __builtin_amdgcn_mfma_f32_16x16x32_bf16(af[u][2], bf[2], za, 0,0,0);
              zb = __builtin_amdgcn_mfma_f32_16x16x32_bf16(af[u][3], bf[3], zb, 0,0,0);
              za = __builtin_amdgcn_mfma_f32_16x16x32_bf16(af[u][4], bf[4], za, 0,0,0);
              zb = __builtin_amdgcn_mfma_f32_16x16x32_bf16(af[u][5], bf[5], zb, 0,0,0);
              z[u] = za + zb;
          }
      }
      const int wp = rp ^ 6144;
      if (prod){
          #pragma unroll
          for (int u = 0; u < 4; ++u){
              if (u < nt){
                  float si = rcp(1.f + ex2(-z[u][0]));
                  float sf = rcp(1.f + ex2(-z[u][1]));
                  float so = rcp(1.f + ex2(-z[u][3]));
                  float tg = 1.f - 2.f*rcp(1.f + ex2(z[u][2] + z[u][2]));
                  cc[u] = sf*cc[u] + si*tg;
                  float th = 1.f - 2.f*rcp(1.f + ex2(twoL*cc[u]));
                  hv[u] = so*th;
                  if (cu[u] < H2)
                      *(unsigned short*)(bb + wp + whb[u]) = f2bf(hv[u]);
              }
          }
      }
      if (tid >= 384 && t + 1 < TP){             // write-late: value loaded at t-1
          unsigned pk = (unsigned)f2bf(xa.x) | ((unsigned)f2bf(xa.y) << 16);
          *(unsigned*)(bb + wp + xwb) = pk;
      }
      xa = xb_;
      rp = wp;
      bar_lds();
  }

  // FC + sigmoid: producer lanes sum their cells, reduce kg groups, then waves
  float p = 0.f;
  if (prod){
      #pragma unroll
      for (int u = 0; u < 4; ++u)
          if (u < nt && cu[u] < H2) p += hv[u] * fw[u];
  }
  p += __shfl_xor(p, 16);
  p += __shfl_xor(p, 32);
  if (l < 4) fcred[w][l] = p;
  __syncthreads();
  if (tid < 4){
      float s = 0.f;
      #pragma unroll
      for (int ww = 0; ww < 8; ++ww) s += fcred[ww][tid];
      s += fcb[0];
      out[b0 + tid] = rcp(1.f + ex2(-s * LOG2E));
  }
}

// ---------------------------------------------------------------------------
extern "C" void kernel_launch(void* const* d_in, const int* in_sizes, int n_in,
                              void* d_out, int out_size, void* d_ws, size_t ws_size,
                              hipStream_t stream) {
    const int*   x_idx = (const int*)  d_in[0];
    const float* emb   = (const float*)d_in[1];
    const float* Wih1  = (const float*)d_in[2];
    const float* Whh1  = (const float*)d_in[3];
    const float* bih1  = (const float*)d_in[4];
    const float* bhh1  = (const float*)d_in[5];
    const float* Wih2  = (const float*)d_in[6];
    const float* Whh2  = (const float*)d_in[7];
    const float* bih2  = (const float*)d_in[8];
    const float* bhh2  = (const float*)d_in[9];
    const float* fcw   = (const float*)d_in[10];
    const float* fcb   = (const float*)d_in[11];
    float* out = (float*)d_out;

    float* table = (float*)d_ws;                       // 21*260*4 = 21840 B
    float* x2    = (float*)((char*)d_ws + 32768);      // 1024*100*64*4 = 26.2 MB

    k_table<<<VOCAB, 256, 0, stream>>>(Wih1, emb, bih1, bhh1, table);
    k_lstm1<<<NB / 4, 256, 0, stream>>>(x_idx, Whh1, table, x2);
    k_lstm2<<<NB / 4, 512, 0, stream>>>(x2, Wih2, Whh2, bih2, bhh2, fcw, fcb, out);
}